// Round 11
// baseline (292.495 us; speedup 1.0000x reference)
//
#include <hip/hip_runtime.h>

typedef __bf16 bf16x8 __attribute__((ext_vector_type(8)));
typedef float f32x4 __attribute__((ext_vector_type(4)));

#define EMB 1024
#define CTXD 768
#define NH 16
#define HD 64
#define BB 8
#define NN 4096
#define MM 77
#define MPAD 96

static __device__ __forceinline__ unsigned short f2bf(float f) {
    unsigned u = __builtin_bit_cast(unsigned, f);
    u += 0x7FFFu + ((u >> 16) & 1u);
    return (unsigned short)(u >> 16);
}

// ------- merged prep: weight transposes + ctx cast + KV zero + mask -------
// z in [0,4): weight transpose+cast plane z
// z == 4  : ctx cast to bf16 with zero pad to 640 rows
// z == 5  : zero K/V padded buffers; one block computes mask lengths
struct PrepArgs {
    const float* wsrc[4];
    unsigned short* wdst[4];
    const float* ctx;
    unsigned short* cbf;
    const unsigned char* mask;
    int* lengths;
    int4* kvzero;   // Kw..Vtw contiguous, 196608 int4s
};
__global__ void prep_kernel(PrepArgs pa) {
    const int z = blockIdx.z;
    const int tx = threadIdx.x, ty = threadIdx.y;
    const int tid = ty * 32 + tx;
    if (z < 4) {
        __shared__ float t[32][33];
        int R = (z < 2) ? 1024 : 768, C = 1024;
        int r0 = blockIdx.y * 32;
        if (r0 >= R) return;
        const float* W = pa.wsrc[z];
        unsigned short* Wt = pa.wdst[z];
        int c0 = blockIdx.x * 32;
#pragma unroll
        for (int i = 0; i < 32; i += 8)
            t[ty + i][tx] = W[(size_t)(r0 + ty + i) * C + c0 + tx];
        __syncthreads();
#pragma unroll
        for (int i = 0; i < 32; i += 8)
            Wt[(size_t)(c0 + ty + i) * R + r0 + tx] = f2bf(t[tx][ty + i]);
    } else if (z == 4) {
        int fid = blockIdx.y * 32 + blockIdx.x;
        int i = fid * 256 + tid;               // int4 index over 640*768/8
        if (i >= 640 * CTXD / 8) return;
        int row = (i * 8) / CTXD;
        union { unsigned short u[8]; int4 v; } r;
        if (row < BB * MM) {
            float4 v0 = ((const float4*)pa.ctx)[2 * i];
            float4 v1 = ((const float4*)pa.ctx)[2 * i + 1];
            r.u[0] = f2bf(v0.x); r.u[1] = f2bf(v0.y);
            r.u[2] = f2bf(v0.z); r.u[3] = f2bf(v0.w);
            r.u[4] = f2bf(v1.x); r.u[5] = f2bf(v1.y);
            r.u[6] = f2bf(v1.z); r.u[7] = f2bf(v1.w);
        } else {
            r.v = make_int4(0, 0, 0, 0);
        }
        ((int4*)pa.cbf)[i] = r.v;
    } else {
        int fid = blockIdx.y * 32 + blockIdx.x;
        int i = fid * 256 + tid;
        if (i < 196608) pa.kvzero[i] = make_int4(0, 0, 0, 0);
        if (fid == 1023 && tid < 64) {
            int ln = tid;
            int anyOdd = 0, anyF = 0;
            for (int k = ln; k < BB * MM; k += 64) {
                unsigned char v = pa.mask[k];
                if (v == 0x80u || v == 0x3Fu) anyF = 1;
                if ((k & 3) && v) anyOdd = 1;
            }
            anyF = __any(anyF); anyOdd = __any(anyOdd);
            int layout = anyF ? 2 : (anyOdd ? 1 : 0);
            int b = ln >> 3, j = ln & 7, cnt = 0;
            for (int m = j; m < MM; m += 8) {
                int idx = b * MM + m;
                int valid;
                if (layout == 1)      valid = pa.mask[idx] != 0;
                else if (layout == 0) valid = ((const int*)pa.mask)[idx] != 0;
                else                  valid = ((const float*)pa.mask)[idx] != 0.0f;
                cnt += valid ? 1 : 0;
            }
            cnt += __shfl_xor(cnt, 1, 64);
            cnt += __shfl_xor(cnt, 2, 64);
            cnt += __shfl_xor(cnt, 4, 64);
            if (j == 0) pa.lengths[b] = cnt;
        }
    }
}

// ============ merged Q-projection (fp32 A direct) + K/V projection ========
// Q branch: A = x (fp32) staged via global_load_lds into fp32 LDS (3 bufs,
// distance 2), converted to bf16 in readA. A-LDS swizzle: 16B-slot ^=
// (row&7) (row = 128 B = one bank cycle); inverse on per-lane global src.
// Per tile 6 loads (A 4 + B 2); boundary vmcnt(6) proves tile t+1.
// B = Wq_t bf16, same staging/swizzle as the proven kernel.
__global__ __launch_bounds__(512, 2) void gemm_q_kv(
    const float* __restrict__ X, const unsigned short* __restrict__ Wq_t,
    const float* __restrict__ bq, unsigned short* __restrict__ Qb,
    const unsigned short* __restrict__ Cbf,
    const unsigned short* __restrict__ Wk_t, const float* __restrict__ bk,
    unsigned short* __restrict__ Kw,
    const unsigned short* __restrict__ Wv_t, const float* __restrict__ bv,
    unsigned short* __restrict__ Vtw) {
    __shared__ char smem[147456];  // A: 3 x 32 KB @0; B: 3 x 16 KB @98304
    const int tid = threadIdx.x, wv = tid >> 6, ln = tid & 63;
    int bid = blockIdx.x;

    if (bid < 80) {
        // ---------------- K/V projection: 128x128 tile, 8 waves ----------
        const bool isV = bid >= 40;
        if (isV) bid -= 40;
        const unsigned short* Bt = isV ? Wv_t : Wk_t;
        const float* bias = isV ? bv : bk;
        { int cpx = 5; bid = (bid & 7) * cpx + (bid >> 3); } // bijective on 40
        const int nt = bid & 7, mt = bid >> 3;
        const int m0 = mt << 7, n0 = nt << 7;
        const int wr = wv >> 2, wc = wv & 3;
        unsigned short* As = (unsigned short*)smem;
        unsigned short* Bs = (unsigned short*)(smem + 8192);

        f32x4 acc[4][2] = {};
        const int rown = ln >> 2, koff = (ln & 3) * 8;
        for (int kt = 0; kt < CTXD; kt += 32) {
            __syncthreads();
            __builtin_amdgcn_global_load_lds(
                (const __attribute__((address_space(1))) void*)(
                    Cbf + (size_t)(m0 + wv * 16 + rown) * CTXD + kt + koff),
                (__attribute__((address_space(3))) void*)(As + wv * 512),
                16, 0, 0);
            __builtin_amdgcn_global_load_lds(
                (const __attribute__((address_space(1))) void*)(
                    Bt + (size_t)(n0 + wv * 16 + rown) * CTXD + kt + koff),
                (__attribute__((address_space(3))) void*)(Bs + wv * 512),
                16, 0, 0);
            __syncthreads();
            bf16x8 af[4], bfr[2];
#pragma unroll
            for (int i = 0; i < 4; ++i)
                af[i] = *(const bf16x8*)(As + (wr * 64 + i * 16 + (ln & 15)) * 32 +
                                         (ln >> 4) * 8);
#pragma unroll
            for (int j = 0; j < 2; ++j)
                bfr[j] = *(const bf16x8*)(Bs + (wc * 32 + j * 16 + (ln & 15)) * 32 +
                                          (ln >> 4) * 8);
#pragma unroll
            for (int i = 0; i < 4; ++i)
#pragma unroll
                for (int j = 0; j < 2; ++j)
                    acc[i][j] = __builtin_amdgcn_mfma_f32_16x16x32_bf16(
                        af[i], bfr[j], acc[i][j], 0, 0, 0);
        }

        float bvals[2];
#pragma unroll
        for (int j = 0; j < 2; ++j)
            bvals[j] = bias[n0 + wc * 32 + j * 16 + (ln & 15)];
#pragma unroll
        for (int i = 0; i < 4; ++i)
#pragma unroll
            for (int j = 0; j < 2; ++j)
#pragma unroll
                for (int r = 0; r < 4; ++r) {
                    int row = m0 + wr * 64 + i * 16 + (ln >> 4) * 4 + r;
                    int col = n0 + wc * 32 + j * 16 + (ln & 15);
                    float v = acc[i][j][r] + bvals[j];
                    if (row < BB * MM) {
                        int bb = row / MM, m = row - bb * MM;
                        int hh = col >> 6, d = col & 63;
                        if (!isV)
                            Kw[((size_t)(bb * NH + hh) * MPAD + m) * HD + d] = f2bf(v);
                        else
                            Vtw[((size_t)(bb * NH + hh) * HD + d) * MPAD + m] = f2bf(v);
                    }
                }
        return;
    }

    // ---------------- Q projection: 256x256, fp32-A, 3-buffer -------------
    bid -= 80;
    const int N = 1024, K = 1024;
    const int nwg = 128 * 4;
    { int cpx = nwg >> 3; bid = (bid & 7) * cpx + (bid >> 3); }
    const int nt_ = bid & 3, mt = bid >> 2;
    const int m0 = mt << 8, n0 = nt_ << 8;
    const int wr = wv >> 2, wc = wv & 3;
    const int NT = K >> 5;  // 32

    const int srowB = wv * 16 + (ln >> 2);   // B staging row (within half)
    const int sslotB = ln & 3;
    const int arowS = wv * 8 + (ln >> 3);    // A staging row (within 64-blk)
    const int aslotS = ln & 7;

    auto stageA = [&](int t, int buf) {
#pragma unroll
        for (int half = 0; half < 2; ++half)
#pragma unroll
            for (int sub = 0; sub < 2; ++sub) {
                int row = half * 128 + sub * 64 + arowS;
                int cs = aslotS ^ (row & 7);
                __builtin_amdgcn_global_load_lds(
                    (const __attribute__((address_space(1))) void*)(
                        X + (size_t)(m0 + row) * K + (t << 5) + cs * 4),
                    (__attribute__((address_space(3))) void*)(
                        smem + buf * 32768 +
                        (half * 128 + sub * 64 + wv * 8) * 128),
                    16, 0, 0);
            }
    };
    auto stageB = [&](int t, int buf) {
#pragma unroll
        for (int half = 0; half < 2; ++half) {
            int row = half * 128 + srowB;
            int gc = sslotB ^ ((row >> 1) & 3);
            __builtin_amdgcn_global_load_lds(
                (const __attribute__((address_space(1))) void*)(
                    Wq_t + (size_t)(n0 + row) * K + (t << 5) + gc * 8),
                (__attribute__((address_space(3))) void*)(
                    smem + 98304 + buf * 16384 +
                    (half * 128 + wv * 16) * 64),
                16, 0, 0);
        }
    };
    auto readA = [&](int buf, int i) -> bf16x8 {
        int arow = wr * 128 + i * 16 + (ln & 15);
        int g = ln >> 4;
        int sA = (2 * g) ^ (arow & 7);
        const float* Af = (const float*)(smem + buf * 32768) + arow * 32;
        f32x4 lo = *(const f32x4*)(Af + sA * 4);        // G cols [8g, 8g+4)
        f32x4 hi = *(const f32x4*)(Af + (sA ^ 1) * 4);  // G cols [8g+4, 8g+8)
        union { unsigned short u[8]; bf16x8 v; } r;
        r.u[0] = f2bf(lo[0]); r.u[1] = f2bf(lo[1]);
        r.u[2] = f2bf(lo[2]); r.u[3] = f2bf(lo[3]);
        r.u[4] = f2bf(hi[0]); r.u[5] = f2bf(hi[1]);
        r.u[6] = f2bf(hi[2]); r.u[7] = f2bf(hi[3]);
        return r.v;
    };
    auto readB = [&](int buf, int j) -> bf16x8 {
        int brow = wc * 64 + j * 16 + (ln & 15);
        int bslot = (ln >> 4) ^ ((brow >> 1) & 3);
        const unsigned short* Bs = (const unsigned short*)(smem + 98304 + buf * 16384);
        return *(const bf16x8*)(Bs + brow * 32 + bslot * 8);
    };

    f32x4 acc[8][4] = {};

    // prologue: stage tiles 0 (buf0) and 1 (buf1); prove tile 0
    stageA(0, 0); stageB(0, 0); stageA(1, 1); stageB(1, 1);
    asm volatile("s_waitcnt vmcnt(6)" ::: "memory");
    __builtin_amdgcn_sched_barrier(0);
    __builtin_amdgcn_s_barrier();

    auto body = [&](int t, int cur, int tgt) {
        if (t >= NT) return;                  // wg-uniform: barrier-safe
        // phase 0
        if (t + 2 < NT) stageA(t + 2, tgt);
        bf16x8 bfr[4], af[4];
#pragma unroll
        for (int j = 0; j < 4; ++j) bfr[j] = readB(cur, j);
#pragma unroll
        for (int i = 0; i < 4; ++i) af[i] = readA(cur, i);
        __builtin_amdgcn_s_barrier();
        __builtin_amdgcn_s_setprio(1);
#pragma unroll
        for (int i = 0; i < 4; ++i)
#pragma unroll
            for (int j = 0; j < 4; ++j)
                acc[i][j] = __builtin_amdgcn_mfma_f32_16x16x32_bf16(
                    af[i], bfr[j], acc[i][j], 0, 0, 0);
        __builtin_amdgcn_s_setprio(0);
        __builtin_amdgcn_s_barrier();
        // phase 1
        if (t + 2 < NT) stageB(t + 2, tgt);
#pragma unroll
        for (int i = 0; i < 4; ++i) af[i] = readA(cur, i + 4);
        __builtin_amdgcn_s_barrier();
        __builtin_amdgcn_s_setprio(1);
#pragma unroll
        for (int i = 0; i < 4; ++i)
#pragma unroll
            for (int j = 0; j < 4; ++j)
                acc[i + 4][j] = __builtin_amdgcn_mfma_f32_16x16x32_bf16(
                    af[i], bfr[j], acc[i + 4][j], 0, 0, 0);
        __builtin_amdgcn_s_setprio(0);
        // boundary: prove tile t+1 (the 6 newest outstanding are t+2's)
        if (t + 2 < NT)      { asm volatile("s_waitcnt vmcnt(6)" ::: "memory"); }
        else if (t + 1 < NT) { asm volatile("s_waitcnt vmcnt(0)" ::: "memory"); }
        __builtin_amdgcn_sched_barrier(0);
        __builtin_amdgcn_s_barrier();
    };

    for (int tb = 0; tb < NT; tb += 3) {   // NT=32; t%3 static per slot
        body(tb + 0, 0, 2);
        body(tb + 1, 1, 0);
        body(tb + 2, 2, 1);
    }

    float bvals[4];
#pragma unroll
    for (int j = 0; j < 4; ++j)
        bvals[j] = bq[n0 + wc * 64 + j * 16 + (ln & 15)];
#pragma unroll
    for (int i = 0; i < 8; ++i)
#pragma unroll
        for (int j = 0; j < 4; ++j)
#pragma unroll
            for (int r = 0; r < 4; ++r) {
                int row = m0 + wr * 128 + i * 16 + (ln >> 4) * 4 + r;
                int col = n0 + wc * 64 + j * 16 + (ln & 15);
                Qb[(size_t)row * N + col] = f2bf(acc[i][j][r] + bvals[j]);
            }
}

// ============ 256x256 deep-pipelined GEMM (O-projection, fp32 out) =======
__global__ __launch_bounds__(512, 2) void gemm256_kernel(
    const unsigned short* __restrict__ A, const unsigned short* __restrict__ Bt,
    const float* __restrict__ bias, float* __restrict__ Cout,
    int M, int N, int K) {
    __shared__ unsigned short lds[4][2][256 * 32];
    const int tid = threadIdx.x, wv = tid >> 6, ln = tid & 63;
    const int numN = N >> 8;
    int bid = blockIdx.x;
    const int nwg = (M >> 8) * numN;
    if ((nwg & 7) == 0) { int cpx = nwg >> 3; bid = (bid & 7) * cpx + (bid >> 3); }
    const int nt_ = bid % numN, mt = bid / numN;
    const int m0 = mt << 8, n0 = nt_ << 8;
    const int wr = wv >> 2, wc = wv & 3;
    const int NT = K >> 5;

    const int srow = wv * 16 + (ln >> 2);
    const int sslot = ln & 3;

    auto stageA = [&](int t) {
#pragma unroll
        for (int half = 0; half < 2; ++half) {
            int row = half * 128 + srow;
            int gc = sslot ^ ((row >> 1) & 3);
            __builtin_amdgcn_global_load_lds(
                (const __attribute__((address_space(1))) void*)(
                    A + (size_t)(m0 + row) * K + (t << 5) + gc * 8),
                (__attribute__((address_space(3))) void*)(
                    &lds[t & 3][0][(half * 128 + wv * 16) * 32]),
                16, 0, 0);
        }
    };
    auto stageB = [&](int t) {
#pragma unroll
        for (int half = 0; half < 2; ++half) {
            int row = half * 128 + srow;
            int gc = sslot ^ ((row >> 1) & 3);
            __builtin_amdgcn_global_load_lds(
                (const __attribute__((address_space(1))) void*)(
                    Bt + (size_t)(n0 + row) * K + (t << 5) + gc * 8),
                (__attribute__((address_space(3))) void*)(
                    &lds[t & 3][1][(half * 128 + wv * 16) * 32]),
                16, 0, 0);
        }
    };
    auto readA = [&](const unsigned short* As, int i) -> bf16x8 {
        int arow = wr * 128 + i * 16 + (ln & 15);
        int aslot = (ln >> 4) ^ ((arow >> 1) & 3);
        return *(const bf16x8*)(As + arow * 32 + aslot * 8);
    };
    auto readB = [&](const unsigned short* Bs, int j) -> bf16x8 {
        int brow = wc * 64 + j * 16 + (ln & 15);
        int bslot = (ln >> 4) ^ ((brow >> 1) & 3);
        return *(const bf16x8*)(Bs + brow * 32 + bslot * 8);
    };

    f32x4 acc[8][4] = {};

    stageA(0); stageB(0); stageA(1); stageB(1); stageA(2); stageB(2);
    asm volatile("s_waitcnt vmcnt(8)" ::: "memory");
    __builtin_amdgcn_sched_barrier(0);
    __builtin_amdgcn_s_barrier();

#pragma unroll 4
    for (int t = 0; t < NT; ++t) {
        const unsigned short* As = lds[t & 3][0];
        const unsigned short* Bs = lds[t & 3][1];
        if (t + 3 < NT) stageA(t + 3);
        bf16x8 bfr[4], af[4];
#pragma unroll
        for (int j = 0; j < 4; ++j) bfr[j] = readB(Bs, j);
#pragma unroll
        for (int i = 0; i < 4; ++i) af[i] = readA(As, i);
        __builtin_amdgcn_s_barrier();
        __builtin_amdgcn_s_setprio(1);
#pragma unroll
        for (int i = 0; i < 4; ++i)
#pragma unroll
            for (int j = 0; j < 4; ++j)
                acc[i][j] = __builtin_amdgcn_mfma_f32_16x16x32_bf16(
                    af[i], bfr[j], acc[i][j], 0, 0, 0);
        __builtin_amdgcn_s_setprio(0);
        __builtin_amdgcn_s_barrier();
        if (t + 3 < NT) stageB(t + 3);
#pragma unroll
        for (int i = 0; i < 4; ++i) af[i] = readA(As, i + 4);
        __builtin_amdgcn_s_barrier();
        __builtin_amdgcn_s_setprio(1);
#pragma unroll
        for (int i = 0; i < 4; ++i)
#pragma unroll
            for (int j = 0; j < 4; ++j)
                acc[i + 4][j] = __builtin_amdgcn_mfma_f32_16x16x32_bf16(
                    af[i], bfr[j], acc[i + 4][j], 0, 0, 0);
        __builtin_amdgcn_s_setprio(0);
        if (t < NT - 1) {
            if (t + 3 < NT)      { asm volatile("s_waitcnt vmcnt(4)" ::: "memory"); }
            else if (t + 2 < NT) { asm volatile("s_waitcnt vmcnt(2)" ::: "memory"); }
            else                 { asm volatile("s_waitcnt vmcnt(0)" ::: "memory"); }
            __builtin_amdgcn_sched_barrier(0);
        }
        __builtin_amdgcn_s_barrier();
    }

    float bvals[4];
#pragma unroll
    for (int j = 0; j < 4; ++j)
        bvals[j] = bias[n0 + wc * 64 + j * 16 + (ln & 15)];
#pragma unroll
    for (int i = 0; i < 8; ++i)
#pragma unroll
        for (int j = 0; j < 4; ++j)
#pragma unroll
            for (int r = 0; r < 4; ++r) {
                int row = m0 + wr * 128 + i * 16 + (ln >> 4) * 4 + r;
                int col = n0 + wc * 64 + j * 16 + (ln & 15);
                Cout[(size_t)row * N + col] = acc[i][j][r] + bvals[j];
            }
}

// ---------------- fused attention v3: 2 q-tiles/wave, V reg-prefetch ------
__global__ __launch_bounds__(256, 3) void attn_kernel(
    const unsigned short* __restrict__ Q, const unsigned short* __restrict__ Kw,
    const unsigned short* __restrict__ Vt, const int* __restrict__ lengths,
    unsigned short* __restrict__ Out) {
    const int bh = blockIdx.y;
    const int b = bh >> 4, h = bh & 15;
    const int q0 = blockIdx.x * 128;
    const int tid = threadIdx.x, wv = tid >> 6, ln = tid & 63;
    const int len = lengths[b];
    const int kscnt = (len + 31) >> 5;

    __shared__ unsigned short Ps[128][104];

    const unsigned short* Ksrc = Kw + (size_t)bh * (MPAD * HD);
    const unsigned short* Vsrc = Vt + (size_t)bh * (HD * MPAD);

    bf16x8 aq[2][2];
#pragma unroll
    for (int qi = 0; qi < 2; ++qi) {
        const int qr = q0 + wv * 32 + qi * 16 + (ln & 15);
        const unsigned short* qptr =
            Q + (size_t)(b * NN + qr) * EMB + h * HD + (ln >> 4) * 8;
        aq[qi][0] = *(const bf16x8*)(qptr);
        aq[qi][1] = *(const bf16x8*)(qptr + 32);
    }

    bf16x8 vf[3][4];
#pragma unroll
    for (int j = 0; j < 4; ++j)
        vf[0][j] = *(const bf16x8*)(Vsrc + (j * 16 + (ln & 15)) * MPAD +
                                    (ln >> 4) * 8);
    if (kscnt > 1) {
#pragma unroll
        for (int j = 0; j < 4; ++j)
            vf[1][j] = *(const bf16x8*)(Vsrc + (j * 16 + (ln & 15)) * MPAD + 32 +
                                        (ln >> 4) * 8);
    }
    if (kscnt > 2) {
#pragma unroll
        for (int j = 0; j < 4; ++j)
            vf[2][j] = *(const bf16x8*)(Vsrc + (j * 16 + (ln & 15)) * MPAD + 64 +
                                        (ln >> 4) * 8);
    }

    f32x4 s[2][5] = {};
#pragma unroll
    for (int t = 0; t < 5; ++t) {
        if (t * 16 < len) {
            const unsigned short* kp =
                Ksrc + (t * 16 + (ln & 15)) * HD + (ln >> 4) * 8;
            bf16x8 k0 = *(const bf16x8*)(kp);
            bf16x8 k1 = *(const bf16x8*)(kp + 32);
#pragma unroll
            for (int qi = 0; qi < 2; ++qi) {
                s[qi][t] = __builtin_amdgcn_mfma_f32_16x16x32_bf16(
                    aq[qi][0], k0, s[qi][t], 0, 0, 0);
                s[qi][t] = __builtin_amdgcn_mfma_f32_16x16x32_bf16(
                    aq[qi][1], k1, s[qi][t], 0, 0, 0);
            }
        }
    }

    const float scale = 0.125f;
    float mx[2][4], sum[2][4];
#pragma unroll
    for (int qi = 0; qi < 2; ++qi)
#pragma unroll
        for (int r = 0; r < 4; ++r) { mx[qi][r] = -1e30f; sum[qi][r] = 0.f; }
#pragma unroll
    for (int t = 0; t < 5; ++t) {
        int m = t * 16 + (ln & 15);
        bool valid = m < len;
#pragma unroll
        for (int qi = 0; qi < 2; ++qi)
#pragma unroll
            for (int r = 0; r < 4; ++r) {
                float v = valid ? s[qi][t][r] * scale : -1e30f;
                s[qi][t][r] = v;
                mx[qi][r] = fmaxf(mx[qi][r], v);
            }
    }
#pragma unroll
    for (int d = 1; d < 16; d <<= 1)
#pragma unroll
        for (int qi = 0; qi < 2; ++qi)
#pragma unroll
            for (int r = 0; r < 4; ++r)
                mx[qi][r] = fmaxf(mx[qi][r], __shfl_xor(mx[qi][r], d, 64));
#pragma unroll
    for (int t = 0; t < 5; ++t)
#pragma unroll
        for (int qi = 0; qi < 2; ++qi)
#pragma unroll
            for (int r = 0; r < 4; ++r) {
                float p = __expf(s[qi][t][r] - mx[qi][r]);
                s[qi][t][r] = p;
                sum[qi][r] += p;
            }
#pragma unroll
    for (int d = 1; d < 16; d <<= 1)
#pragma unroll
        for (int qi = 0; qi < 2; ++qi)
#pragma unroll
            for (int r = 0; r < 4; ++r)
                sum[qi][r] += __shfl_xor(sum[qi][r], d, 64);

    float rinv[2][4];
#pragma unroll
    for (int qi = 0; qi < 2; ++qi)
#pragma unroll
        for (int r = 0; r < 4; ++r) rinv[qi][r] = 1.0f / sum[qi][r];

#pragma unroll
    for (int t = 0; t < 6; ++t)
#pragma unroll
        for (int qi = 0; qi < 2; ++qi)
#pragma unroll
            for (int r = 0; r < 4; ++r) {
                int row = wv * 32 + qi * 16 + (ln >> 4) * 4 + r;
                float v = (t < 5) ? s[qi][t][r] * rinv[qi][r] : 0.0f;
                Ps[row][t * 16 + (ln & 15)] = f2bf(v);
            }

    f32x4 o[2][4] = {};
    for (int ks = 0; ks < kscnt; ++ks) {
#pragma unroll
        for (int qi = 0; qi < 2; ++qi) {
            bf16x8 pf = *(const bf16x8*)(&Ps[wv * 32 + qi * 16 + (ln & 15)]
                                            [ks * 32 + (ln >> 4) * 8]);
#pragma unroll
            for (int j = 0; j < 4; ++j)
                o[qi][j] = __builtin_amdgcn_mfma_f32_16x16x32_bf16(
                    vf[ks][j], pf, o[qi][j], 0, 0, 0);
        }
    }

#pragma unroll
    for (int qi = 0; qi < 2; ++qi) {
        const int qrow = q0 + wv * 32 + qi * 16 + (ln & 15);
        unsigned short* obase =
            Out + (size_t)(b * NN + qrow) * EMB + h * HD + (ln >> 4) * 4;
#pragma unroll
        for (int j = 0; j < 4; ++j) {
            union { unsigned short u[4]; unsigned long long ll; } pk;
#pragma unroll
            for (int r = 0; r < 4; ++r) pk.u[r] = f2bf(o[qi][j][r]);
            *(unsigned long long*)(obase + j * 16) = pk.ll;
        }
    }
}

// ---------------- launch ----------------
extern "C" void kernel_launch(void* const* d_in, const int* in_sizes, int n_in,
                              void* d_out, int out_size, void* d_ws, size_t ws_size,
                              hipStream_t stream) {
    const float* x    = (const float*)d_in[0];
    const float* ctx  = (const float*)d_in[1];
    const unsigned char* cmask = (const unsigned char*)d_in[2];
    const float* Wq = (const float*)d_in[3];
    const float* bq = (const float*)d_in[4];
    const float* Wk = (const float*)d_in[5];
    const float* bk = (const float*)d_in[6];
    const float* Wv = (const float*)d_in[7];
    const float* bv = (const float*)d_in[8];
    const float* Wo = (const float*)d_in[9];
    const float* bo = (const float*)d_in[10];

    char* ws = (char*)d_ws;
    unsigned short* Xbf   = (unsigned short*)(ws);              // attn-out, 64 MiB
    unsigned short* Wq_t  = (unsigned short*)(ws + 67108864);   // 2 MiB
    unsigned short* Wo_t  = (unsigned short*)(ws + 69206016);   // 2 MiB
    unsigned short* Wk_t  = (unsigned short*)(ws + 71303168);   // 1.5 MiB
    unsigned short* Wv_t  = (unsigned short*)(ws + 72876032);   // 1.5 MiB
    unsigned short* Cbf   = (unsigned short*)(ws + 74448896);   // 640x768 bf16
    unsigned short* Kw    = (unsigned short*)(ws + 75431936);   // 128x96x64 bf16
    unsigned short* Vtw   = (unsigned short*)(ws + 77004800);   // 128x64x96 bf16
    int* lengths          = (int*)(ws + 78577664);
    unsigned short* Qb    = (unsigned short*)d_out;             // 64 MiB scratch

    PrepArgs pa;
    pa.wsrc[0] = Wq; pa.wsrc[1] = Wo; pa.wsrc[2] = Wk; pa.wsrc[3] = Wv;
    pa.wdst[0] = Wq_t; pa.wdst[1] = Wo_t; pa.wdst[2] = Wk_t; pa.wdst[3] = Wv_t;
    pa.ctx = ctx; pa.cbf = Cbf; pa.mask = cmask; pa.lengths = lengths;
    pa.kvzero = (int4*)Kw;   // Kw + Vtw contiguous (2 x 1.5 MiB)
    prep_kernel<<<dim3(32, 32, 6), dim3(32, 8), 0, stream>>>(pa);

    gemm_q_kv<<<592, 512, 0, stream>>>(x, Wq_t, bq, Qb,
                                       Cbf, Wk_t, bk, Kw, Wv_t, bv, Vtw);

    attn_kernel<<<dim3(32, 128), 256, 0, stream>>>(Qb, Kw, Vtw, lengths, Xbf);

    gemm256_kernel<<<512, 512, 0, stream>>>(Xbf, Wo_t, bo, (float*)d_out,
                                            32768, 1024, 1024);
}

// Round 12
// 264.306 us; speedup vs baseline: 1.1067x; 1.1067x over previous
//
#include <hip/hip_runtime.h>

typedef __bf16 bf16x8 __attribute__((ext_vector_type(8)));
typedef float f32x4 __attribute__((ext_vector_type(4)));

#define EMB 1024
#define CTXD 768
#define NH 16
#define HD 64
#define BB 8
#define NN 4096
#define MM 77
#define MPAD 96

static __device__ __forceinline__ unsigned short f2bf(float f) {
    unsigned u = __builtin_bit_cast(unsigned, f);
    u += 0x7FFFu + ((u >> 16) & 1u);
    return (unsigned short)(u >> 16);
}

// ------- merged prep: weight transposes + ctx cast + KV zero + mask + x cast
// z in [0,4): weight transpose+cast plane z
// z == 4  : ctx cast to bf16 with zero pad to 640 rows
// z == 5  : zero K/V padded buffers; one block computes mask lengths
// z in [6,22): x fp32 -> bf16 cast (4,194,304 int4 chunks over 16 planes)
struct PrepArgs {
    const float* wsrc[4];
    unsigned short* wdst[4];
    const float* ctx;
    unsigned short* cbf;
    const unsigned char* mask;
    int* lengths;
    int4* kvzero;   // Kw..Vtw contiguous, 196608 int4s
    const float* x;
    unsigned short* xbf;
};
__global__ void prep_kernel(PrepArgs pa) {
    const int z = blockIdx.z;
    const int tx = threadIdx.x, ty = threadIdx.y;
    const int tid = ty * 32 + tx;
    if (z < 4) {
        __shared__ float t[32][33];
        int R = (z < 2) ? 1024 : 768, C = 1024;
        int r0 = blockIdx.y * 32;
        if (r0 >= R) return;
        const float* W = pa.wsrc[z];
        unsigned short* Wt = pa.wdst[z];
#pragma unroll
        for (int i = 0; i < 32; i += 8)
            t[ty + i][tx] = W[(size_t)(r0 + ty + i) * C + blockIdx.x * 32 + tx];
        __syncthreads();
        int c0 = blockIdx.x * 32;
#pragma unroll
        for (int i = 0; i < 32; i += 8)
            Wt[(size_t)(c0 + ty + i) * R + r0 + tx] = f2bf(t[tx][ty + i]);
    } else if (z == 4) {
        int fid = blockIdx.y * 32 + blockIdx.x;
        int i = fid * 256 + tid;               // int4 index over 640*768/8
        if (i >= 640 * CTXD / 8) return;
        int row = (i * 8) / CTXD;
        union { unsigned short u[8]; int4 v; } r;
        if (row < BB * MM) {
            float4 v0 = ((const float4*)pa.ctx)[2 * i];
            float4 v1 = ((const float4*)pa.ctx)[2 * i + 1];
            r.u[0] = f2bf(v0.x); r.u[1] = f2bf(v0.y);
            r.u[2] = f2bf(v0.z); r.u[3] = f2bf(v0.w);
            r.u[4] = f2bf(v1.x); r.u[5] = f2bf(v1.y);
            r.u[6] = f2bf(v1.z); r.u[7] = f2bf(v1.w);
        } else {
            r.v = make_int4(0, 0, 0, 0);
        }
        ((int4*)pa.cbf)[i] = r.v;
    } else if (z == 5) {
        int fid = blockIdx.y * 32 + blockIdx.x;
        int i = fid * 256 + tid;
        if (i < 196608) pa.kvzero[i] = make_int4(0, 0, 0, 0);
        if (fid == 1023 && tid < 64) {
            int ln = tid;
            int anyOdd = 0, anyF = 0;
            for (int k = ln; k < BB * MM; k += 64) {
                unsigned char v = pa.mask[k];
                if (v == 0x80u || v == 0x3Fu) anyF = 1;
                if ((k & 3) && v) anyOdd = 1;
            }
            anyF = __any(anyF); anyOdd = __any(anyOdd);
            int layout = anyF ? 2 : (anyOdd ? 1 : 0);
            int b = ln >> 3, j = ln & 7, cnt = 0;
            for (int m = j; m < MM; m += 8) {
                int idx = b * MM + m;
                int valid;
                if (layout == 1)      valid = pa.mask[idx] != 0;
                else if (layout == 0) valid = ((const int*)pa.mask)[idx] != 0;
                else                  valid = ((const float*)pa.mask)[idx] != 0.0f;
                cnt += valid ? 1 : 0;
            }
            cnt += __shfl_xor(cnt, 1, 64);
            cnt += __shfl_xor(cnt, 2, 64);
            cnt += __shfl_xor(cnt, 4, 64);
            if (j == 0) pa.lengths[b] = cnt;
        }
    } else {
        // x cast: plane z-6 of 16, each 1024 blocks x 256 threads x 1 int4
        int i = ((z - 6) * 1024 + blockIdx.y * 32 + blockIdx.x) * 256 + tid;
        float4 v0 = ((const float4*)pa.x)[2 * i];
        float4 v1 = ((const float4*)pa.x)[2 * i + 1];
        union { unsigned short u[8]; int4 v; } r;
        r.u[0] = f2bf(v0.x); r.u[1] = f2bf(v0.y);
        r.u[2] = f2bf(v0.z); r.u[3] = f2bf(v0.w);
        r.u[4] = f2bf(v1.x); r.u[5] = f2bf(v1.y);
        r.u[6] = f2bf(v1.z); r.u[7] = f2bf(v1.w);
        ((int4*)pa.xbf)[i] = r.v;
    }
}

// ============ merged Q-projection (256x256 pipelined) + K/V projection ====
// grid = 592 x 512 threads. bid in [0,80): K/V projection (issued first so
// it fills CUs while the 512 Q wgs stream); bid in [80,592): Q GEMM.
__global__ __launch_bounds__(512, 2) void gemm_q_kv(
    const unsigned short* __restrict__ Xbf, const unsigned short* __restrict__ Wq_t,
    const float* __restrict__ bq, unsigned short* __restrict__ Qb,
    const unsigned short* __restrict__ Cbf,
    const unsigned short* __restrict__ Wk_t, const float* __restrict__ bk,
    unsigned short* __restrict__ Kw,
    const unsigned short* __restrict__ Wv_t, const float* __restrict__ bv,
    unsigned short* __restrict__ Vtw) {
    __shared__ unsigned short lds[4][2][256 * 32]; // 128 KiB
    const int tid = threadIdx.x, wv = tid >> 6, ln = tid & 63;
    int bid = blockIdx.x;

    if (bid < 80) {
        // ---------------- K/V projection: 128x128 tile, 8 waves ----------
        const bool isV = bid >= 40;
        if (isV) bid -= 40;
        const unsigned short* Bt = isV ? Wv_t : Wk_t;
        const float* bias = isV ? bv : bk;
        { int cpx = 5; bid = (bid & 7) * cpx + (bid >> 3); } // bijective on 40
        const int nt = bid & 7, mt = bid >> 3;
        const int m0 = mt << 7, n0 = nt << 7;
        const int wr = wv >> 2, wc = wv & 3;
        unsigned short* As = &lds[0][0][0];
        unsigned short* Bs = &lds[0][1][0];

        f32x4 acc[4][2] = {};
        const int rown = ln >> 2, koff = (ln & 3) * 8;
        for (int kt = 0; kt < CTXD; kt += 32) {
            __syncthreads();
            __builtin_amdgcn_global_load_lds(
                (const __attribute__((address_space(1))) void*)(
                    Cbf + (size_t)(m0 + wv * 16 + rown) * CTXD + kt + koff),
                (__attribute__((address_space(3))) void*)(As + wv * 512),
                16, 0, 0);
            __builtin_amdgcn_global_load_lds(
                (const __attribute__((address_space(1))) void*)(
                    Bt + (size_t)(n0 + wv * 16 + rown) * CTXD + kt + koff),
                (__attribute__((address_space(3))) void*)(Bs + wv * 512),
                16, 0, 0);
            __syncthreads();
            bf16x8 af[4], bfr[2];
#pragma unroll
            for (int i = 0; i < 4; ++i)
                af[i] = *(const bf16x8*)(As + (wr * 64 + i * 16 + (ln & 15)) * 32 +
                                         (ln >> 4) * 8);
#pragma unroll
            for (int j = 0; j < 2; ++j)
                bfr[j] = *(const bf16x8*)(Bs + (wc * 32 + j * 16 + (ln & 15)) * 32 +
                                          (ln >> 4) * 8);
#pragma unroll
            for (int i = 0; i < 4; ++i)
#pragma unroll
                for (int j = 0; j < 2; ++j)
                    acc[i][j] = __builtin_amdgcn_mfma_f32_16x16x32_bf16(
                        af[i], bfr[j], acc[i][j], 0, 0, 0);
        }

        float bvals[2];
#pragma unroll
        for (int j = 0; j < 2; ++j)
            bvals[j] = bias[n0 + wc * 32 + j * 16 + (ln & 15)];
#pragma unroll
        for (int i = 0; i < 4; ++i)
#pragma unroll
            for (int j = 0; j < 2; ++j)
#pragma unroll
                for (int r = 0; r < 4; ++r) {
                    int row = m0 + wr * 64 + i * 16 + (ln >> 4) * 4 + r;
                    int col = n0 + wc * 32 + j * 16 + (ln & 15);
                    float v = acc[i][j][r] + bvals[j];
                    if (row < BB * MM) {
                        int bb = row / MM, m = row - bb * MM;
                        int hh = col >> 6, d = col & 63;
                        if (!isV)
                            Kw[((size_t)(bb * NH + hh) * MPAD + m) * HD + d] = f2bf(v);
                        else
                            Vtw[((size_t)(bb * NH + hh) * HD + d) * MPAD + m] = f2bf(v);
                    }
                }
        return;
    }

    // ---------------- Q projection: 256x256 deep-pipelined GEMM ----------
    bid -= 80;
    const int M = 32768, N = 1024, K = 1024;
    const int numN = N >> 8;
    const int nwg = (M >> 8) * numN;
    { int cpx = nwg >> 3; bid = (bid & 7) * cpx + (bid >> 3); }
    const int nt_ = bid % numN, mt = bid / numN;
    const int m0 = mt << 8, n0 = nt_ << 8;
    const int wr = wv >> 2, wc = wv & 3;
    const int NT = K >> 5;

    const int srow = wv * 16 + (ln >> 2);
    const int sslot = ln & 3;

    auto stageA = [&](int t) {
#pragma unroll
        for (int half = 0; half < 2; ++half) {
            int row = half * 128 + srow;
            int gc = sslot ^ ((row >> 1) & 3);
            __builtin_amdgcn_global_load_lds(
                (const __attribute__((address_space(1))) void*)(
                    Xbf + (size_t)(m0 + row) * K + (t << 5) + gc * 8),
                (__attribute__((address_space(3))) void*)(
                    &lds[t & 3][0][(half * 128 + wv * 16) * 32]),
                16, 0, 0);
        }
    };
    auto stageB = [&](int t) {
#pragma unroll
        for (int half = 0; half < 2; ++half) {
            int row = half * 128 + srow;
            int gc = sslot ^ ((row >> 1) & 3);
            __builtin_amdgcn_global_load_lds(
                (const __attribute__((address_space(1))) void*)(
                    Wq_t + (size_t)(n0 + row) * K + (t << 5) + gc * 8),
                (__attribute__((address_space(3))) void*)(
                    &lds[t & 3][1][(half * 128 + wv * 16) * 32]),
                16, 0, 0);
        }
    };
    auto readA = [&](const unsigned short* As, int i) -> bf16x8 {
        int arow = wr * 128 + i * 16 + (ln & 15);
        int aslot = (ln >> 4) ^ ((arow >> 1) & 3);
        return *(const bf16x8*)(As + arow * 32 + aslot * 8);
    };
    auto readB = [&](const unsigned short* Bs, int j) -> bf16x8 {
        int brow = wc * 64 + j * 16 + (ln & 15);
        int bslot = (ln >> 4) ^ ((brow >> 1) & 3);
        return *(const bf16x8*)(Bs + brow * 32 + bslot * 8);
    };

    f32x4 acc[8][4] = {};

    stageA(0); stageB(0); stageA(1); stageB(1); stageA(2); stageB(2);
    asm volatile("s_waitcnt vmcnt(8)" ::: "memory");
    __builtin_amdgcn_sched_barrier(0);
    __builtin_amdgcn_s_barrier();

#pragma unroll 4
    for (int t = 0; t < NT; ++t) {
        const unsigned short* As = lds[t & 3][0];
        const unsigned short* Bs = lds[t & 3][1];
        if (t + 3 < NT) stageA(t + 3);
        bf16x8 bfr[4], af[4];
#pragma unroll
        for (int j = 0; j < 4; ++j) bfr[j] = readB(Bs, j);
#pragma unroll
        for (int i = 0; i < 4; ++i) af[i] = readA(As, i);
        __builtin_amdgcn_s_barrier();
        __builtin_amdgcn_s_setprio(1);
#pragma unroll
        for (int i = 0; i < 4; ++i)
#pragma unroll
            for (int j = 0; j < 4; ++j)
                acc[i][j] = __builtin_amdgcn_mfma_f32_16x16x32_bf16(
                    af[i], bfr[j], acc[i][j], 0, 0, 0);
        __builtin_amdgcn_s_setprio(0);
        __builtin_amdgcn_s_barrier();
        if (t + 3 < NT) stageB(t + 3);
#pragma unroll
        for (int i = 0; i < 4; ++i) af[i] = readA(As, i + 4);
        __builtin_amdgcn_s_barrier();
        __builtin_amdgcn_s_setprio(1);
#pragma unroll
        for (int i = 0; i < 4; ++i)
#pragma unroll
            for (int j = 0; j < 4; ++j)
                acc[i + 4][j] = __builtin_amdgcn_mfma_f32_16x16x32_bf16(
                    af[i], bfr[j], acc[i + 4][j], 0, 0, 0);
        __builtin_amdgcn_s_setprio(0);
        if (t < NT - 1) {
            if (t + 3 < NT)      { asm volatile("s_waitcnt vmcnt(4)" ::: "memory"); }
            else if (t + 2 < NT) { asm volatile("s_waitcnt vmcnt(2)" ::: "memory"); }
            else                 { asm volatile("s_waitcnt vmcnt(0)" ::: "memory"); }
            __builtin_amdgcn_sched_barrier(0);
        }
        __builtin_amdgcn_s_barrier();
    }

    float bvals[4];
#pragma unroll
    for (int j = 0; j < 4; ++j)
        bvals[j] = bq[n0 + wc * 64 + j * 16 + (ln & 15)];
#pragma unroll
    for (int i = 0; i < 8; ++i)
#pragma unroll
        for (int j = 0; j < 4; ++j)
#pragma unroll
            for (int r = 0; r < 4; ++r) {
                int row = m0 + wr * 128 + i * 16 + (ln >> 4) * 4 + r;
                int col = n0 + wc * 64 + j * 16 + (ln & 15);
                Qb[(size_t)row * N + col] = f2bf(acc[i][j][r] + bvals[j]);
            }
}

// ============ 256x256 deep-pipelined GEMM (O-projection, fp32 out) =======
__global__ __launch_bounds__(512, 2) void gemm256_kernel(
    const unsigned short* __restrict__ A, const unsigned short* __restrict__ Bt,
    const float* __restrict__ bias, float* __restrict__ Cout,
    int M, int N, int K) {
    __shared__ unsigned short lds[4][2][256 * 32];
    const int tid = threadIdx.x, wv = tid >> 6, ln = tid & 63;
    const int numN = N >> 8;
    int bid = blockIdx.x;
    const int nwg = (M >> 8) * numN;
    if ((nwg & 7) == 0) { int cpx = nwg >> 3; bid = (bid & 7) * cpx + (bid >> 3); }
    const int nt_ = bid % numN, mt = bid / numN;
    const int m0 = mt << 8, n0 = nt_ << 8;
    const int wr = wv >> 2, wc = wv & 3;
    const int NT = K >> 5;

    const int srow = wv * 16 + (ln >> 2);
    const int sslot = ln & 3;

    auto stageA = [&](int t) {
#pragma unroll
        for (int half = 0; half < 2; ++half) {
            int row = half * 128 + srow;
            int gc = sslot ^ ((row >> 1) & 3);
            __builtin_amdgcn_global_load_lds(
                (const __attribute__((address_space(1))) void*)(
                    A + (size_t)(m0 + row) * K + (t << 5) + gc * 8),
                (__attribute__((address_space(3))) void*)(
                    &lds[t & 3][0][(half * 128 + wv * 16) * 32]),
                16, 0, 0);
        }
    };
    auto stageB = [&](int t) {
#pragma unroll
        for (int half = 0; half < 2; ++half) {
            int row = half * 128 + srow;
            int gc = sslot ^ ((row >> 1) & 3);
            __builtin_amdgcn_global_load_lds(
                (const __attribute__((address_space(1))) void*)(
                    Bt + (size_t)(n0 + row) * K + (t << 5) + gc * 8),
                (__attribute__((address_space(3))) void*)(
                    &lds[t & 3][1][(half * 128 + wv * 16) * 32]),
                16, 0, 0);
        }
    };
    auto readA = [&](const unsigned short* As, int i) -> bf16x8 {
        int arow = wr * 128 + i * 16 + (ln & 15);
        int aslot = (ln >> 4) ^ ((arow >> 1) & 3);
        return *(const bf16x8*)(As + arow * 32 + aslot * 8);
    };
    auto readB = [&](const unsigned short* Bs, int j) -> bf16x8 {
        int brow = wc * 64 + j * 16 + (ln & 15);
        int bslot = (ln >> 4) ^ ((brow >> 1) & 3);
        return *(const bf16x8*)(Bs + brow * 32 + bslot * 8);
    };

    f32x4 acc[8][4] = {};

    stageA(0); stageB(0); stageA(1); stageB(1); stageA(2); stageB(2);
    asm volatile("s_waitcnt vmcnt(8)" ::: "memory");
    __builtin_amdgcn_sched_barrier(0);
    __builtin_amdgcn_s_barrier();

#pragma unroll 4
    for (int t = 0; t < NT; ++t) {
        const unsigned short* As = lds[t & 3][0];
        const unsigned short* Bs = lds[t & 3][1];
        if (t + 3 < NT) stageA(t + 3);
        bf16x8 bfr[4], af[4];
#pragma unroll
        for (int j = 0; j < 4; ++j) bfr[j] = readB(Bs, j);
#pragma unroll
        for (int i = 0; i < 4; ++i) af[i] = readA(As, i);
        __builtin_amdgcn_s_barrier();
        __builtin_amdgcn_s_setprio(1);
#pragma unroll
        for (int i = 0; i < 4; ++i)
#pragma unroll
            for (int j = 0; j < 4; ++j)
                acc[i][j] = __builtin_amdgcn_mfma_f32_16x16x32_bf16(
                    af[i], bfr[j], acc[i][j], 0, 0, 0);
        __builtin_amdgcn_s_setprio(0);
        __builtin_amdgcn_s_barrier();
        if (t + 3 < NT) stageB(t + 3);
#pragma unroll
        for (int i = 0; i < 4; ++i) af[i] = readA(As, i + 4);
        __builtin_amdgcn_s_barrier();
        __builtin_amdgcn_s_setprio(1);
#pragma unroll
        for (int i = 0; i < 4; ++i)
#pragma unroll
            for (int j = 0; j < 4; ++j)
                acc[i + 4][j] = __builtin_amdgcn_mfma_f32_16x16x32_bf16(
                    af[i], bfr[j], acc[i + 4][j], 0, 0, 0);
        __builtin_amdgcn_s_setprio(0);
        if (t < NT - 1) {
            if (t + 3 < NT)      { asm volatile("s_waitcnt vmcnt(4)" ::: "memory"); }
            else if (t + 2 < NT) { asm volatile("s_waitcnt vmcnt(2)" ::: "memory"); }
            else                 { asm volatile("s_waitcnt vmcnt(0)" ::: "memory"); }
            __builtin_amdgcn_sched_barrier(0);
        }
        __builtin_amdgcn_s_barrier();
    }

    float bvals[4];
#pragma unroll
    for (int j = 0; j < 4; ++j)
        bvals[j] = bias[n0 + wc * 64 + j * 16 + (ln & 15)];
#pragma unroll
    for (int i = 0; i < 8; ++i)
#pragma unroll
        for (int j = 0; j < 4; ++j)
#pragma unroll
            for (int r = 0; r < 4; ++r) {
                int row = m0 + wr * 128 + i * 16 + (ln >> 4) * 4 + r;
                int col = n0 + wc * 64 + j * 16 + (ln & 15);
                Cout[(size_t)row * N + col] = acc[i][j][r] + bvals[j];
            }
}

// ---------------- fused attention v3: 2 q-tiles/wave, V reg-prefetch ------
__global__ __launch_bounds__(256, 3) void attn_kernel(
    const unsigned short* __restrict__ Q, const unsigned short* __restrict__ Kw,
    const unsigned short* __restrict__ Vt, const int* __restrict__ lengths,
    unsigned short* __restrict__ Out) {
    const int bh = blockIdx.y;
    const int b = bh >> 4, h = bh & 15;
    const int q0 = blockIdx.x * 128;
    const int tid = threadIdx.x, wv = tid >> 6, ln = tid & 63;
    const int len = lengths[b];
    const int kscnt = (len + 31) >> 5;

    __shared__ unsigned short Ps[128][104];

    const unsigned short* Ksrc = Kw + (size_t)bh * (MPAD * HD);
    const unsigned short* Vsrc = Vt + (size_t)bh * (HD * MPAD);

    bf16x8 aq[2][2];
#pragma unroll
    for (int qi = 0; qi < 2; ++qi) {
        const int qr = q0 + wv * 32 + qi * 16 + (ln & 15);
        const unsigned short* qptr =
            Q + (size_t)(b * NN + qr) * EMB + h * HD + (ln >> 4) * 8;
        aq[qi][0] = *(const bf16x8*)(qptr);
        aq[qi][1] = *(const bf16x8*)(qptr + 32);
    }

    bf16x8 vf[3][4];
#pragma unroll
    for (int j = 0; j < 4; ++j)
        vf[0][j] = *(const bf16x8*)(Vsrc + (j * 16 + (ln & 15)) * MPAD +
                                    (ln >> 4) * 8);
    if (kscnt > 1) {
#pragma unroll
        for (int j = 0; j < 4; ++j)
            vf[1][j] = *(const bf16x8*)(Vsrc + (j * 16 + (ln & 15)) * MPAD + 32 +
                                        (ln >> 4) * 8);
    }
    if (kscnt > 2) {
#pragma unroll
        for (int j = 0; j < 4; ++j)
            vf[2][j] = *(const bf16x8*)(Vsrc + (j * 16 + (ln & 15)) * MPAD + 64 +
                                        (ln >> 4) * 8);
    }

    f32x4 s[2][5] = {};
#pragma unroll
    for (int t = 0; t < 5; ++t) {
        if (t * 16 < len) {
            const unsigned short* kp =
                Ksrc + (t * 16 + (ln & 15)) * HD + (ln >> 4) * 8;
            bf16x8 k0 = *(const bf16x8*)(kp);
            bf16x8 k1 = *(const bf16x8*)(kp + 32);
#pragma unroll
            for (int qi = 0; qi < 2; ++qi) {
                s[qi][t] = __builtin_amdgcn_mfma_f32_16x16x32_bf16(
                    aq[qi][0], k0, s[qi][t], 0, 0, 0);
                s[qi][t] = __builtin_amdgcn_mfma_f32_16x16x32_bf16(
                    aq[qi][1], k1, s[qi][t], 0, 0, 0);
            }
        }
    }

    const float scale = 0.125f;
    float mx[2][4], sum[2][4];
#pragma unroll
    for (int qi = 0; qi < 2; ++qi)
#pragma unroll
        for (int r = 0; r < 4; ++r) { mx[qi][r] = -1e30f; sum[qi][r] = 0.f; }
#pragma unroll
    for (int t = 0; t < 5; ++t) {
        int m = t * 16 + (ln & 15);
        bool valid = m < len;
#pragma unroll
        for (int qi = 0; qi < 2; ++qi)
#pragma unroll
            for (int r = 0; r < 4; ++r) {
                float v = valid ? s[qi][t][r] * scale : -1e30f;
                s[qi][t][r] = v;
                mx[qi][r] = fmaxf(mx[qi][r], v);
            }
    }
#pragma unroll
    for (int d = 1; d < 16; d <<= 1)
#pragma unroll
        for (int qi = 0; qi < 2; ++qi)
#pragma unroll
            for (int r = 0; r < 4; ++r)
                mx[qi][r] = fmaxf(mx[qi][r], __shfl_xor(mx[qi][r], d, 64));
#pragma unroll
    for (int t = 0; t < 5; ++t)
#pragma unroll
        for (int qi = 0; qi < 2; ++qi)
#pragma unroll
            for (int r = 0; r < 4; ++r) {
                float p = __expf(s[qi][t][r] - mx[qi][r]);
                s[qi][t][r] = p;
                sum[qi][r] += p;
            }
#pragma unroll
    for (int d = 1; d < 16; d <<= 1)
#pragma unroll
        for (int qi = 0; qi < 2; ++qi)
#pragma unroll
            for (int r = 0; r < 4; ++r)
                sum[qi][r] += __shfl_xor(sum[qi][r], d, 64);

    float rinv[2][4];
#pragma unroll
    for (int qi = 0; qi < 2; ++qi)
#pragma unroll
        for (int r = 0; r < 4; ++r) rinv[qi][r] = 1.0f / sum[qi][r];

#pragma unroll
    for (int t = 0; t < 6; ++t)
#pragma unroll
        for (int qi = 0; qi < 2; ++qi)
#pragma unroll
            for (int r = 0; r < 4; ++r) {
                int row = wv * 32 + qi * 16 + (ln >> 4) * 4 + r;
                float v = (t < 5) ? s[qi][t][r] * rinv[qi][r] : 0.0f;
                Ps[row][t * 16 + (ln & 15)] = f2bf(v);
            }

    f32x4 o[2][4] = {};
    for (int ks = 0; ks < kscnt; ++ks) {
#pragma unroll
        for (int qi = 0; qi < 2; ++qi) {
            bf16x8 pf = *(const bf16x8*)(&Ps[wv * 32 + qi * 16 + (ln & 15)]
                                            [ks * 32 + (ln >> 4) * 8]);
#pragma unroll
            for (int j = 0; j < 4; ++j)
                o[qi][j] = __builtin_amdgcn_mfma_f32_16x16x32_bf16(
                    vf[ks][j], pf, o[qi][j], 0, 0, 0);
        }
    }

#pragma unroll
    for (int qi = 0; qi < 2; ++qi) {
        const int qrow = q0 + wv * 32 + qi * 16 + (ln & 15);
        unsigned short* obase =
            Out + (size_t)(b * NN + qrow) * EMB + h * HD + (ln >> 4) * 4;
#pragma unroll
        for (int j = 0; j < 4; ++j) {
            union { unsigned short u[4]; unsigned long long ll; } pk;
#pragma unroll
            for (int r = 0; r < 4; ++r) pk.u[r] = f2bf(o[qi][j][r]);
            *(unsigned long long*)(obase + j * 16) = pk.ll;
        }
    }
}

// ---------------- launch ----------------
extern "C" void kernel_launch(void* const* d_in, const int* in_sizes, int n_in,
                              void* d_out, int out_size, void* d_ws, size_t ws_size,
                              hipStream_t stream) {
    const float* x    = (const float*)d_in[0];
    const float* ctx  = (const float*)d_in[1];
    const unsigned char* cmask = (const unsigned char*)d_in[2];
    const float* Wq = (const float*)d_in[3];
    const float* bq = (const float*)d_in[4];
    const float* Wk = (const float*)d_in[5];
    const float* bk = (const float*)d_in[6];
    const float* Wv = (const float*)d_in[7];
    const float* bv = (const float*)d_in[8];
    const float* Wo = (const float*)d_in[9];
    const float* bo = (const float*)d_in[10];

    char* ws = (char*)d_ws;
    unsigned short* Xbf   = (unsigned short*)(ws);              // attn-out, 64 MiB
    unsigned short* Wq_t  = (unsigned short*)(ws + 67108864);   // 2 MiB
    unsigned short* Wo_t  = (unsigned short*)(ws + 69206016);   // 2 MiB
    unsigned short* Wk_t  = (unsigned short*)(ws + 71303168);   // 1.5 MiB
    unsigned short* Wv_t  = (unsigned short*)(ws + 72876032);   // 1.5 MiB
    unsigned short* Cbf   = (unsigned short*)(ws + 74448896);   // 640x768 bf16
    unsigned short* Kw    = (unsigned short*)(ws + 75431936);   // 128x96x64 bf16
    unsigned short* Vtw   = (unsigned short*)(ws + 77004800);   // 128x64x96 bf16
    int* lengths          = (int*)(ws + 78577664);
    unsigned short* Qb    = (unsigned short*)d_out;             // 64 MiB scratch

    PrepArgs pa;
    pa.wsrc[0] = Wq; pa.wsrc[1] = Wo; pa.wsrc[2] = Wk; pa.wsrc[3] = Wv;
    pa.wdst[0] = Wq_t; pa.wdst[1] = Wo_t; pa.wdst[2] = Wk_t; pa.wdst[3] = Wv_t;
    pa.ctx = ctx; pa.cbf = Cbf; pa.mask = cmask; pa.lengths = lengths;
    pa.kvzero = (int4*)Kw;   // Kw + Vtw contiguous (2 x 1.5 MiB)
    pa.x = x; pa.xbf = Xbf;
    prep_kernel<<<dim3(32, 32, 22), dim3(32, 8), 0, stream>>>(pa);

    gemm_q_kv<<<592, 512, 0, stream>>>(Xbf, Wq_t, bq, Qb,
                                       Cbf, Wk_t, bk, Kw, Wv_t, bv, Vtw);

    attn_kernel<<<dim3(32, 128), 256, 0, stream>>>(Qb, Kw, Vtw, lengths, Xbf);

    gemm256_kernel<<<512, 512, 0, stream>>>(Xbf, Wo_t, bo, (float*)d_out,
                                            32768, 1024, 1024);
}